// Round 8
// baseline (455.673 us; speedup 1.0000x reference)
//
#include <hip/hip_runtime.h>

#define E_DIM 1024

typedef __attribute__((ext_vector_type(8))) short bf16x8;
typedef __attribute__((ext_vector_type(8))) int i32x8;
typedef __attribute__((ext_vector_type(4))) float f32x4;
typedef unsigned long long u64;

// ---- monotone float->uint so unsigned min == float min ----
__device__ __forceinline__ unsigned f2mono(float f) {
  unsigned u = __float_as_uint(f);
  return (u & 0x80000000u) ? ~u : (u | 0x80000000u);
}
// pack two fp32 into bf16x2 (truncation) with one v_perm_b32 (fallback path)
__device__ __forceinline__ unsigned pk_bf16(float lo, float hi) {
  return __builtin_amdgcn_perm(__float_as_uint(hi), __float_as_uint(lo), 0x07060302u);
}
// async global->LDS, 16B per lane: lds image = lane-ordered copy of 1KB/wave
__device__ __forceinline__ void dma16(const void* g, void* l) {
  __builtin_amdgcn_global_load_lds(
      (const __attribute__((address_space(1))) unsigned*)g,
      (__attribute__((address_space(3))) unsigned*)l, 16, 0, 0);
}

// Kernel 1: fused norms-partials + fp32->fp8 convert, ONE pass over A and P.
// Block = (rb of 128 rows, kg of 4 k-chunks). Each thread: row=t>>1, half=t&1,
// 16 k per chunk per matrix. Writes fp8 chunks (4KB layout bytes[(q*128+row)*8+j],
// the MFMA fragment order) and per-(kg,row) partial sums (deterministic, no atomics).
__global__ __launch_bounds__(256) void normsconv_kernel(
    const float* __restrict__ A, const float* __restrict__ P,
    unsigned char* __restrict__ At, unsigned char* __restrict__ Pt,
    float* __restrict__ pa, float* __restrict__ pp, float* __restrict__ pab,
    int B) {
  const int rb = blockIdx.x >> 3;
  const int kg = blockIdx.x & 7;
  const int t = threadIdx.x;
  const int row = t >> 1;
  const int half = t & 1;
  const int grow = rb * 128 + row;
  float sa = 0.f, sp = 0.f, sab = 0.f;
#pragma unroll
  for (int i = 0; i < 4; ++i) {
    const int kb = kg * 4 + i;
    const float* sa4 = A + (size_t)grow * E_DIM + kb * 32 + half * 16;
    const float* sp4 = P + (size_t)grow * E_DIM + kb * 32 + half * 16;
    float4 a0 = ((const float4*)sa4)[0], a1 = ((const float4*)sa4)[1];
    float4 a2 = ((const float4*)sa4)[2], a3 = ((const float4*)sa4)[3];
    float4 p0 = ((const float4*)sp4)[0], p1 = ((const float4*)sp4)[1];
    float4 p2 = ((const float4*)sp4)[2], p3 = ((const float4*)sp4)[3];
    sa += a0.x*a0.x + a0.y*a0.y + a0.z*a0.z + a0.w*a0.w
        + a1.x*a1.x + a1.y*a1.y + a1.z*a1.z + a1.w*a1.w
        + a2.x*a2.x + a2.y*a2.y + a2.z*a2.z + a2.w*a2.w
        + a3.x*a3.x + a3.y*a3.y + a3.z*a3.z + a3.w*a3.w;
    sp += p0.x*p0.x + p0.y*p0.y + p0.z*p0.z + p0.w*p0.w
        + p1.x*p1.x + p1.y*p1.y + p1.z*p1.z + p1.w*p1.w
        + p2.x*p2.x + p2.y*p2.y + p2.z*p2.z + p2.w*p2.w
        + p3.x*p3.x + p3.y*p3.y + p3.z*p3.z + p3.w*p3.w;
    sab += a0.x*p0.x + a0.y*p0.y + a0.z*p0.z + a0.w*p0.w
         + a1.x*p1.x + a1.y*p1.y + a1.z*p1.z + a1.w*p1.w
         + a2.x*p2.x + a2.y*p2.y + a2.z*p2.z + a2.w*p2.w
         + a3.x*p3.x + a3.y*p3.y + a3.z*p3.z + a3.w*p3.w;
    int d0 = __builtin_amdgcn_cvt_pk_fp8_f32(a0.x, a0.y, 0, 0);
    d0 = __builtin_amdgcn_cvt_pk_fp8_f32(a0.z, a0.w, d0, 1);
    int d1 = __builtin_amdgcn_cvt_pk_fp8_f32(a1.x, a1.y, 0, 0);
    d1 = __builtin_amdgcn_cvt_pk_fp8_f32(a1.z, a1.w, d1, 1);
    int d2 = __builtin_amdgcn_cvt_pk_fp8_f32(a2.x, a2.y, 0, 0);
    d2 = __builtin_amdgcn_cvt_pk_fp8_f32(a2.z, a2.w, d2, 1);
    int d3 = __builtin_amdgcn_cvt_pk_fp8_f32(a3.x, a3.y, 0, 0);
    d3 = __builtin_amdgcn_cvt_pk_fp8_f32(a3.z, a3.w, d3, 1);
    int e0 = __builtin_amdgcn_cvt_pk_fp8_f32(p0.x, p0.y, 0, 0);
    e0 = __builtin_amdgcn_cvt_pk_fp8_f32(p0.z, p0.w, e0, 1);
    int e1 = __builtin_amdgcn_cvt_pk_fp8_f32(p1.x, p1.y, 0, 0);
    e1 = __builtin_amdgcn_cvt_pk_fp8_f32(p1.z, p1.w, e1, 1);
    int e2 = __builtin_amdgcn_cvt_pk_fp8_f32(p2.x, p2.y, 0, 0);
    e2 = __builtin_amdgcn_cvt_pk_fp8_f32(p2.z, p2.w, e2, 1);
    int e3 = __builtin_amdgcn_cvt_pk_fp8_f32(p3.x, p3.y, 0, 0);
    e3 = __builtin_amdgcn_cvt_pk_fp8_f32(p3.z, p3.w, e3, 1);
    const size_t cb = (size_t)(rb * 32 + kb) * 4096;
    uint2 alo = {(unsigned)d0, (unsigned)d1};
    uint2 ahi = {(unsigned)d2, (unsigned)d3};
    uint2 plo = {(unsigned)e0, (unsigned)e1};
    uint2 phi = {(unsigned)e2, (unsigned)e3};
    *(uint2*)(At + cb + ((2 * half + 0) * 128 + row) * 8) = alo;
    *(uint2*)(At + cb + ((2 * half + 1) * 128 + row) * 8) = ahi;
    *(uint2*)(Pt + cb + ((2 * half + 0) * 128 + row) * 8) = plo;
    *(uint2*)(Pt + cb + ((2 * half + 1) * 128 + row) * 8) = phi;
  }
  // combine the two half-row threads (adjacent lanes) and store partials
  sa  += __shfl_xor(sa, 1);
  sp  += __shfl_xor(sp, 1);
  sab += __shfl_xor(sab, 1);
  if (half == 0) {
    pa[kg * B + grow] = sa;
    pp[kg * B + grow] = sp;
    pab[kg * B + grow] = sab;
  }
}

// Kernel 1c: finalize norms: inv_na/inv_np/exact ap, init top-2 arrays.
__global__ __launch_bounds__(256) void finalize_kernel(
    const float* __restrict__ pa, const float* __restrict__ pp,
    const float* __restrict__ pab, float* __restrict__ inv_na,
    float* __restrict__ inv_np, float* __restrict__ ap,
    u64* __restrict__ arr1, u64* __restrict__ arr2, int B) {
  const int row = blockIdx.x * 256 + threadIdx.x;
  if (row >= B) return;
  float sa = 0.f, sp = 0.f, sab = 0.f;
#pragma unroll
  for (int kg = 0; kg < 8; ++kg) {
    sa += pa[kg * B + row];
    sp += pp[kg * B + row];
    sab += pab[kg * B + row];
  }
  float ina = 1.0f / sqrtf(sa);
  float inp = 1.0f / sqrtf(sp);
  inv_na[row] = ina;
  inv_np[row] = inp;
  ap[row] = sab * ina * inp;
  arr1[row] = 0xFFFFFFFFFFFFFFFFULL;
  arr2[row] = 0xFFFFFFFFFFFFFFFFULL;
}

// Kernel 2: MX-scaled fp8 MFMA GEMM (16x16x128, unity e8m0 scales -> plain
// fp8 matmul at 2x the non-scaled rate). 128x128 tile, 4 waves, BK=128,
// 8 barrier windows, 16 MFMA/wave/window, global_load_lds staging, XCD
// swizzle. Per-window k-permutation inside the 128-K block is harmless:
// identical A/B fragment layouts make the dot product permutation-invariant.
// Fused per-row TOP-2 + two-stage atomicMin merge; exact repair in an2.
__global__ __launch_bounds__(256) void simmin_fp8mx(
    const unsigned char* __restrict__ At, const unsigned char* __restrict__ Pt,
    const float* __restrict__ inv_np, u64* __restrict__ arr1,
    u64* __restrict__ arr2, int nb) {
  __shared__ __align__(16) unsigned char As[16384];  // 4 chunks of 4KB
  __shared__ __align__(16) unsigned char Ps[16384];

  const int lid = blockIdx.x;
  int by, bx;
  if (nb == 64) {  // 8x8 supertiles of 8x8 blocks, one supertile set per XCD
    const int xcd = lid & 7;
    const int s = lid >> 3;
    const int st = xcd * 8 + (s >> 6);
    const int u = s & 63;
    by = (st >> 3) * 8 + (u >> 3);
    bx = (st & 7) * 8 + (u & 7);
  } else {
    by = lid / nb;
    bx = lid % nb;
  }

  const int tid = threadIdx.x;
  const int wave = tid >> 6, lane = tid & 63;
  const int wr = wave >> 1, wc = wave & 1;
  const int rowBase = by * 128;
  const int colBase = bx * 128;
  const int c = lane & 15, q = lane >> 4;

  f32x4 acc[4][4];
#pragma unroll
  for (int mt = 0; mt < 4; ++mt)
#pragma unroll
    for (int nt = 0; nt < 4; ++nt) acc[mt][nt] = (f32x4){0.f, 0.f, 0.f, 0.f};

  const unsigned char* Ab = At + (size_t)by * (32 * 4096);  // 128KB slab
  const unsigned char* Pb = Pt + (size_t)bx * (32 * 4096);
  const int loff = wave * 4096;  // each wave stages one 4KB chunk per matrix
  const int goff = loff + lane * 16;

  // lane's fragment: row = wr*64 + mt*16 + c, k-block q -> chunk q of window,
  // 4 x 8B slices at q2*1024 within that chunk.
  const int abase = q * 4096 + (wr * 64 + c) * 8;
  const int bbase = q * 4096 + (wc * 64 + c) * 8;

  for (int kt = 0; kt < 8; ++kt) {  // BK=128: 4 chunks per matrix per window
    const unsigned char* ca = Ab + kt * 16384;
    const unsigned char* cp = Pb + kt * 16384;
    dma16(ca + goff, As + loff);
    dma16(ca + goff + 1024, As + loff + 1024);
    dma16(ca + goff + 2048, As + loff + 2048);
    dma16(ca + goff + 3072, As + loff + 3072);
    dma16(cp + goff, Ps + loff);
    dma16(cp + goff + 1024, Ps + loff + 1024);
    dma16(cp + goff + 2048, Ps + loff + 2048);
    dma16(cp + goff + 3072, Ps + loff + 3072);
    __syncthreads();  // vmcnt(0) drain + barrier

    i32x8 av[4], bv[4];
#pragma unroll
    for (int mt = 0; mt < 4; ++mt) {
      const unsigned char* ab = &As[abase + mt * 128];
      uint2 t0 = *(const uint2*)(ab);
      uint2 t1 = *(const uint2*)(ab + 1024);
      uint2 t2 = *(const uint2*)(ab + 2048);
      uint2 t3 = *(const uint2*)(ab + 3072);
      av[mt] = (i32x8){(int)t0.x, (int)t0.y, (int)t1.x, (int)t1.y,
                       (int)t2.x, (int)t2.y, (int)t3.x, (int)t3.y};
    }
#pragma unroll
    for (int nt = 0; nt < 4; ++nt) {
      const unsigned char* pb = &Ps[bbase + nt * 128];
      uint2 t0 = *(const uint2*)(pb);
      uint2 t1 = *(const uint2*)(pb + 1024);
      uint2 t2 = *(const uint2*)(pb + 2048);
      uint2 t3 = *(const uint2*)(pb + 3072);
      bv[nt] = (i32x8){(int)t0.x, (int)t0.y, (int)t1.x, (int)t1.y,
                       (int)t2.x, (int)t2.y, (int)t3.x, (int)t3.y};
    }
#pragma unroll
    for (int mt = 0; mt < 4; ++mt)
#pragma unroll
      for (int nt = 0; nt < 4; ++nt)
        acc[mt][nt] = __builtin_amdgcn_mfma_scale_f32_16x16x128_f8f6f4(
            av[mt], bv[nt], acc[mt][nt], 0, 0,  // cbsz=0 (fp8), blgp=0 (fp8)
            0, 0x7F7F7F7Fu,                     // A: opsel 0, unity e8m0
            0, 0x7F7F7F7Fu);                    // B: opsel 0, unity e8m0
    __syncthreads();
  }

  // Epilogue: per-row top-2 of v = dot*inv_np[col], j != i.
  // C/D layout (shape-determined): col = lane&15 (=c), row = q*4 + reg.
  float inp_l[4];
#pragma unroll
  for (int nt = 0; nt < 4; ++nt)
    inp_l[nt] = inv_np[colBase + wc * 64 + nt * 16 + c];

#pragma unroll
  for (int mt = 0; mt < 4; ++mt) {
#pragma unroll
    for (int reg = 0; reg < 4; ++reg) {
      const int gi = rowBase + wr * 64 + mt * 16 + q * 4 + reg;
      float v1 = 3.4e38f, v2 = 3.4e38f;
      int i1 = 0, i2 = 0;
#pragma unroll
      for (int nt = 0; nt < 4; ++nt) {
        const int gj = colBase + wc * 64 + nt * 16 + c;
        float v = acc[mt][nt][reg] * inp_l[nt];
        if (gj != gi) {
          if (v < v1) { v2 = v1; i2 = i1; v1 = v; i1 = gj; }
          else if (v < v2) { v2 = v; i2 = gj; }
        }
      }
#pragma unroll
      for (int off = 1; off < 16; off <<= 1) {
        float ov1 = __shfl_xor(v1, off); int oi1 = __shfl_xor(i1, off);
        float ov2 = __shfl_xor(v2, off); int oi2 = __shfl_xor(i2, off);
        float l; int li;
        if (ov1 < v1) { l = v1; li = i1; v1 = ov1; i1 = oi1; }
        else          { l = ov1; li = oi1; }
        if (ov2 < v2) { v2 = ov2; i2 = oi2; }
        if (l < v2)   { v2 = l; i2 = li; }
      }
      if (c == 0) {
        u64 p1 = ((u64)f2mono(v1) << 32) | (unsigned)i1;
        u64 p2 = ((u64)f2mono(v2) << 32) | (unsigned)i2;
        u64 old = atomicMin(&arr1[gi], p1);
        u64 l2 = (old < p1) ? p1 : old;  // loser of the arr1 battle
        if (p2 < l2) l2 = p2;
        atomicMin(&arr2[gi], l2);
      }
    }
  }
}

// Kernel 3: exact fp32 cos for BOTH top-2 candidates; an = min. 1 wave/row.
__global__ __launch_bounds__(256) void an2_kernel(
    const float* __restrict__ A, const float* __restrict__ P,
    const float* __restrict__ inv_na, const float* __restrict__ inv_np,
    const u64* __restrict__ arr1, const u64* __restrict__ arr2,
    float* __restrict__ an, int B) {
  const int row = blockIdx.x * 4 + (threadIdx.x >> 6);
  const int lane = threadIdx.x & 63;
  const unsigned j1 = (unsigned)(arr1[row] & 0xFFFFFFFFULL) & (unsigned)(B - 1);
  const unsigned j2 = (unsigned)(arr2[row] & 0xFFFFFFFFULL) & (unsigned)(B - 1);
  const float4* a4 = (const float4*)(A + (size_t)row * E_DIM);
  const float4* p4a = (const float4*)(P + (size_t)j1 * E_DIM);
  const float4* p4b = (const float4*)(P + (size_t)j2 * E_DIM);
  float s1 = 0.f, s2 = 0.f;
#pragma unroll
  for (int v = 0; v < 4; ++v) {
    const int ci = v * 64 + lane;
    float4 a = a4[ci];
    float4 p = p4a[ci];
    float4 r = p4b[ci];
    s1 += a.x * p.x + a.y * p.y + a.z * p.z + a.w * p.w;
    s2 += a.x * r.x + a.y * r.y + a.z * r.z + a.w * r.w;
  }
#pragma unroll
  for (int off = 32; off > 0; off >>= 1) {
    s1 += __shfl_down(s1, off);
    s2 += __shfl_down(s2, off);
  }
  if (lane == 0) {
    float ina = inv_na[row];
    float c1 = s1 * ina * inv_np[j1];
    float c2 = s2 * ina * inv_np[j2];
    an[row] = (c1 < c2) ? c1 : c2;
  }
}

// Kernel 4: loss_i = relu(1 + ap_i - an_i); out = mean.
__global__ __launch_bounds__(256) void loss_kernel(
    const float* __restrict__ ap, const float* __restrict__ an,
    float* __restrict__ out, int B) {
  const int t = threadIdx.x;
  float s = 0.f;
  for (int i = t; i < B; i += 256) {
    float l = 1.0f + ap[i] - an[i];
    s += (l > 0.f) ? l : 0.f;
  }
#pragma unroll
  for (int off = 32; off > 0; off >>= 1) s += __shfl_down(s, off);
  __shared__ float red[4];
  const int wave = t >> 6, lane = t & 63;
  if (lane == 0) red[wave] = s;
  __syncthreads();
  if (t == 0) out[0] = (red[0] + red[1] + red[2] + red[3]) / (float)B;
}

// ---------- fallback path (ws too small): round-3-proven bf16 pipeline ----
__global__ __launch_bounds__(256) void norms_kernel(
    const float* __restrict__ A, const float* __restrict__ P,
    float* __restrict__ inv_na, float* __restrict__ inv_np,
    float* __restrict__ ap, u64* __restrict__ min64) {
  const int row = blockIdx.x;
  const int t = threadIdx.x;
  const float4* a4 = (const float4*)(A + (size_t)row * E_DIM);
  const float4* p4 = (const float4*)(P + (size_t)row * E_DIM);
  float sa = 0.f, sp = 0.f, sab = 0.f;
  for (int c = t; c < E_DIM / 4; c += 256) {
    float4 a = a4[c];
    float4 p = p4[c];
    sa  += a.x * a.x + a.y * a.y + a.z * a.z + a.w * a.w;
    sp  += p.x * p.x + p.y * p.y + p.z * p.z + p.w * p.w;
    sab += a.x * p.x + a.y * p.y + a.z * p.z + a.w * p.w;
  }
#pragma unroll
  for (int off = 32; off > 0; off >>= 1) {
    sa  += __shfl_down(sa, off);
    sp  += __shfl_down(sp, off);
    sab += __shfl_down(sab, off);
  }
  __shared__ float red[4][3];
  const int wave = t >> 6, lane = t & 63;
  if (lane == 0) { red[wave][0] = sa; red[wave][1] = sp; red[wave][2] = sab; }
  __syncthreads();
  if (t == 0) {
    sa  = red[0][0] + red[1][0] + red[2][0] + red[3][0];
    sp  = red[0][1] + red[1][1] + red[2][1] + red[3][1];
    sab = red[0][2] + red[1][2] + red[2][2] + red[3][2];
    float ina = 1.0f / sqrtf(sa);
    float inp = 1.0f / sqrtf(sp);
    inv_na[row] = ina;
    inv_np[row] = inp;
    ap[row] = sab * ina * inp;
    min64[row] = 0xFFFFFFFFFFFFFFFFULL;
  }
}

__global__ __launch_bounds__(256) void simmin_mfma(
    const float* __restrict__ A, const float* __restrict__ P,
    const float* __restrict__ inv_np, u64* __restrict__ min64) {
  __shared__ __align__(16) short As[128 * 40];
  __shared__ __align__(16) short Ps[128 * 40];

  const int tid = threadIdx.x;
  const int wave = tid >> 6, lane = tid & 63;
  const int wr = wave >> 1, wc = wave & 1;
  const int rowBase = blockIdx.y * 128;
  const int colBase = blockIdx.x * 128;
  const int c = lane & 15, q = lane >> 4;

  f32x4 acc[4][4];
#pragma unroll
  for (int mt = 0; mt < 4; ++mt)
#pragma unroll
    for (int nt = 0; nt < 4; ++nt) acc[mt][nt] = (f32x4){0.f, 0.f, 0.f, 0.f};

  const int sm = tid >> 1;
  const int sh = (tid & 1) * 16;
  const float* Ab = A + (size_t)(rowBase + sm) * E_DIM + sh;
  const float* Pb = P + (size_t)(colBase + sm) * E_DIM + sh;
  uint4* AsW = (uint4*)&As[sm * 40 + sh];
  uint4* PsW = (uint4*)&Ps[sm * 40 + sh];

  for (int kt = 0; kt < E_DIM; kt += 32) {
    float4 a0 = *(const float4*)(Ab + kt);
    float4 a1 = *(const float4*)(Ab + kt + 4);
    float4 a2 = *(const float4*)(Ab + kt + 8);
    float4 a3 = *(const float4*)(Ab + kt + 12);
    float4 p0 = *(const float4*)(Pb + kt);
    float4 p1 = *(const float4*)(Pb + kt + 4);
    float4 p2 = *(const float4*)(Pb + kt + 8);
    float4 p3 = *(const float4*)(Pb + kt + 12);
    uint4 av0 = {pk_bf16(a0.x, a0.y), pk_bf16(a0.z, a0.w),
                 pk_bf16(a1.x, a1.y), pk_bf16(a1.z, a1.w)};
    uint4 av1 = {pk_bf16(a2.x, a2.y), pk_bf16(a2.z, a2.w),
                 pk_bf16(a3.x, a3.y), pk_bf16(a3.z, a3.w)};
    uint4 pv0 = {pk_bf16(p0.x, p0.y), pk_bf16(p0.z, p0.w),
                 pk_bf16(p1.x, p1.y), pk_bf16(p1.z, p1.w)};
    uint4 pv1 = {pk_bf16(p2.x, p2.y), pk_bf16(p2.z, p2.w),
                 pk_bf16(p3.x, p3.y), pk_bf16(p3.z, p3.w)};
    AsW[0] = av0; AsW[1] = av1;
    PsW[0] = pv0; PsW[1] = pv1;
    __syncthreads();

    bf16x8 af[4], bfr[4];
#pragma unroll
    for (int mt = 0; mt < 4; ++mt)
      af[mt] = *(const bf16x8*)&As[(wr * 64 + mt * 16 + c) * 40 + q * 8];
#pragma unroll
    for (int nt = 0; nt < 4; ++nt)
      bfr[nt] = *(const bf16x8*)&Ps[(wc * 64 + nt * 16 + c) * 40 + q * 8];
#pragma unroll
    for (int mt = 0; mt < 4; ++mt)
#pragma unroll
      for (int nt = 0; nt < 4; ++nt)
        acc[mt][nt] = __builtin_amdgcn_mfma_f32_16x16x32_bf16(
            af[mt], bfr[nt], acc[mt][nt], 0, 0, 0);
    __syncthreads();
  }

  float inp_l[4];
#pragma unroll
  for (int nt = 0; nt < 4; ++nt)
    inp_l[nt] = inv_np[colBase + wc * 64 + nt * 16 + c];

#pragma unroll
  for (int mt = 0; mt < 4; ++mt) {
#pragma unroll
    for (int reg = 0; reg < 4; ++reg) {
      const int gi = rowBase + wr * 64 + mt * 16 + q * 4 + reg;
      float best = 3.4e38f;
      int bidx2 = 0;
#pragma unroll
      for (int nt = 0; nt < 4; ++nt) {
        const int gj = colBase + wc * 64 + nt * 16 + c;
        float v = acc[mt][nt][reg] * inp_l[nt];
        if (gj != gi && v < best) { best = v; bidx2 = gj; }
      }
#pragma unroll
      for (int off = 1; off < 16; off <<= 1) {
        float ov = __shfl_xor(best, off);
        int oi = __shfl_xor(bidx2, off);
        if (ov < best) { best = ov; bidx2 = oi; }
      }
      if (c == 0) {
        u64 pk = ((u64)f2mono(best) << 32) | (unsigned)bidx2;
        atomicMin(&min64[gi], pk);
      }
    }
  }
}

extern "C" void kernel_launch(void* const* d_in, const int* in_sizes, int n_in,
                              void* d_out, int out_size, void* d_ws, size_t ws_size,
                              hipStream_t stream) {
  const float* A = (const float*)d_in[0];  // anchor  [B][1024] fp32
  const float* P = (const float*)d_in[1];  // positive[B][1024] fp32
  const int B = in_sizes[0] / E_DIM;       // 8192

  const size_t fp8_elems = (size_t)B * E_DIM;  // bytes per fp8 matrix
  // At | Pt | arr1 | arr2 | partials(3 x 8B floats) | inv_na | inv_np | ap | an
  const size_t need = 2 * fp8_elems + (size_t)B * (16 + 96 + 16) + 64;
  const int nb = B / 128;

  if (ws_size >= need) {
    unsigned char* At = (unsigned char*)d_ws;
    unsigned char* Pt = At + fp8_elems;
    u64* arr1 = (u64*)(Pt + fp8_elems);   // 8B-aligned (16MB offset)
    u64* arr2 = arr1 + B;
    float* pa = (float*)(arr2 + B);
    float* pp = pa + 8 * B;
    float* pab = pp + 8 * B;
    float* inv_na = pab + 8 * B;
    float* inv_np = inv_na + B;
    float* ap = inv_np + B;
    float* an = ap + B;

    normsconv_kernel<<<nb * 8, 256, 0, stream>>>(A, P, At, Pt, pa, pp, pab, B);
    finalize_kernel<<<(B + 255) / 256, 256, 0, stream>>>(
        pa, pp, pab, inv_na, inv_np, ap, arr1, arr2, B);
    simmin_fp8mx<<<nb * nb, 256, 0, stream>>>(At, Pt, inv_np, arr1, arr2, nb);
    an2_kernel<<<B / 4, 256, 0, stream>>>(A, P, inv_na, inv_np, arr1, arr2, an, B);
    loss_kernel<<<1, 256, 0, stream>>>(ap, an, (float*)d_out, B);
  } else {
    float* inv_na = (float*)d_ws;
    float* inv_np = inv_na + B;
    float* ap = inv_np + B;
    float* an = ap + B;
    u64* min64 = (u64*)(an + B);
    dim3 grid(nb, nb);

    norms_kernel<<<B, 256, 0, stream>>>(A, P, inv_na, inv_np, ap, min64);
    simmin_mfma<<<grid, 256, 0, stream>>>(A, P, inv_np, min64);
    an2_kernel<<<B / 4, 256, 0, stream>>>(A, P, inv_na, inv_np, min64, min64, an, B);
    loss_kernel<<<1, 256, 0, stream>>>(ap, an, (float*)d_out, B);
  }
}

// Round 9
// 287.253 us; speedup vs baseline: 1.5863x; 1.5863x over previous
//
#include <hip/hip_runtime.h>

#define E_DIM 1024

typedef __attribute__((ext_vector_type(8))) short bf16x8;
typedef __attribute__((ext_vector_type(4))) float f32x4;
typedef unsigned long long u64;

// ---- monotone float->uint so unsigned min == float min ----
__device__ __forceinline__ unsigned f2mono(float f) {
  unsigned u = __float_as_uint(f);
  return (u & 0x80000000u) ? ~u : (u | 0x80000000u);
}
// pack two fp32 into bf16x2 (truncation) with one v_perm_b32 (fallback path)
__device__ __forceinline__ unsigned pk_bf16(float lo, float hi) {
  return __builtin_amdgcn_perm(__float_as_uint(hi), __float_as_uint(lo), 0x07060302u);
}
// async global->LDS, 16B per lane: lds image = lane-ordered copy of 1KB/wave
__device__ __forceinline__ void dma16(const void* g, void* l) {
  __builtin_amdgcn_global_load_lds(
      (const __attribute__((address_space(1))) unsigned*)g,
      (__attribute__((address_space(3))) unsigned*)l, 16, 0, 0);
}

// Kernel 1: fused norms-partials + fp32->fp8 convert, ONE pass over A and P.
// Block = (rb of 128 rows, kg of 4 k-chunks). Each thread: row=t>>1, half=t&1.
// Writes fp8 chunks (4KB layout bytes[(q*128+row)*8+j], the MFMA fragment
// order) and per-(kg,row) partial sums (deterministic, no atomics).
__global__ __launch_bounds__(256) void normsconv_kernel(
    const float* __restrict__ A, const float* __restrict__ P,
    unsigned char* __restrict__ At, unsigned char* __restrict__ Pt,
    float* __restrict__ pa, float* __restrict__ pp, float* __restrict__ pab,
    int B) {
  const int rb = blockIdx.x >> 3;
  const int kg = blockIdx.x & 7;
  const int t = threadIdx.x;
  const int row = t >> 1;
  const int half = t & 1;
  const int grow = rb * 128 + row;
  float sa = 0.f, sp = 0.f, sab = 0.f;
#pragma unroll
  for (int i = 0; i < 4; ++i) {
    const int kb = kg * 4 + i;
    const float* sa4 = A + (size_t)grow * E_DIM + kb * 32 + half * 16;
    const float* sp4 = P + (size_t)grow * E_DIM + kb * 32 + half * 16;
    float4 a0 = ((const float4*)sa4)[0], a1 = ((const float4*)sa4)[1];
    float4 a2 = ((const float4*)sa4)[2], a3 = ((const float4*)sa4)[3];
    float4 p0 = ((const float4*)sp4)[0], p1 = ((const float4*)sp4)[1];
    float4 p2 = ((const float4*)sp4)[2], p3 = ((const float4*)sp4)[3];
    sa += a0.x*a0.x + a0.y*a0.y + a0.z*a0.z + a0.w*a0.w
        + a1.x*a1.x + a1.y*a1.y + a1.z*a1.z + a1.w*a1.w
        + a2.x*a2.x + a2.y*a2.y + a2.z*a2.z + a2.w*a2.w
        + a3.x*a3.x + a3.y*a3.y + a3.z*a3.z + a3.w*a3.w;
    sp += p0.x*p0.x + p0.y*p0.y + p0.z*p0.z + p0.w*p0.w
        + p1.x*p1.x + p1.y*p1.y + p1.z*p1.z + p1.w*p1.w
        + p2.x*p2.x + p2.y*p2.y + p2.z*p2.z + p2.w*p2.w
        + p3.x*p3.x + p3.y*p3.y + p3.z*p3.z + p3.w*p3.w;
    sab += a0.x*p0.x + a0.y*p0.y + a0.z*p0.z + a0.w*p0.w
         + a1.x*p1.x + a1.y*p1.y + a1.z*p1.z + a1.w*p1.w
         + a2.x*p2.x + a2.y*p2.y + a2.z*p2.z + a2.w*p2.w
         + a3.x*p3.x + a3.y*p3.y + a3.z*p3.z + a3.w*p3.w;
    int d0 = __builtin_amdgcn_cvt_pk_fp8_f32(a0.x, a0.y, 0, 0);
    d0 = __builtin_amdgcn_cvt_pk_fp8_f32(a0.z, a0.w, d0, 1);
    int d1 = __builtin_amdgcn_cvt_pk_fp8_f32(a1.x, a1.y, 0, 0);
    d1 = __builtin_amdgcn_cvt_pk_fp8_f32(a1.z, a1.w, d1, 1);
    int d2 = __builtin_amdgcn_cvt_pk_fp8_f32(a2.x, a2.y, 0, 0);
    d2 = __builtin_amdgcn_cvt_pk_fp8_f32(a2.z, a2.w, d2, 1);
    int d3 = __builtin_amdgcn_cvt_pk_fp8_f32(a3.x, a3.y, 0, 0);
    d3 = __builtin_amdgcn_cvt_pk_fp8_f32(a3.z, a3.w, d3, 1);
    int e0 = __builtin_amdgcn_cvt_pk_fp8_f32(p0.x, p0.y, 0, 0);
    e0 = __builtin_amdgcn_cvt_pk_fp8_f32(p0.z, p0.w, e0, 1);
    int e1 = __builtin_amdgcn_cvt_pk_fp8_f32(p1.x, p1.y, 0, 0);
    e1 = __builtin_amdgcn_cvt_pk_fp8_f32(p1.z, p1.w, e1, 1);
    int e2 = __builtin_amdgcn_cvt_pk_fp8_f32(p2.x, p2.y, 0, 0);
    e2 = __builtin_amdgcn_cvt_pk_fp8_f32(p2.z, p2.w, e2, 1);
    int e3 = __builtin_amdgcn_cvt_pk_fp8_f32(p3.x, p3.y, 0, 0);
    e3 = __builtin_amdgcn_cvt_pk_fp8_f32(p3.z, p3.w, e3, 1);
    const size_t cb = (size_t)(rb * 32 + kb) * 4096;
    uint2 alo = {(unsigned)d0, (unsigned)d1};
    uint2 ahi = {(unsigned)d2, (unsigned)d3};
    uint2 plo = {(unsigned)e0, (unsigned)e1};
    uint2 phi = {(unsigned)e2, (unsigned)e3};
    *(uint2*)(At + cb + ((2 * half + 0) * 128 + row) * 8) = alo;
    *(uint2*)(At + cb + ((2 * half + 1) * 128 + row) * 8) = ahi;
    *(uint2*)(Pt + cb + ((2 * half + 0) * 128 + row) * 8) = plo;
    *(uint2*)(Pt + cb + ((2 * half + 1) * 128 + row) * 8) = phi;
  }
  // combine the two half-row threads (adjacent lanes) and store partials
  sa  += __shfl_xor(sa, 1);
  sp  += __shfl_xor(sp, 1);
  sab += __shfl_xor(sab, 1);
  if (half == 0) {
    pa[kg * B + grow] = sa;
    pp[kg * B + grow] = sp;
    pab[kg * B + grow] = sab;
  }
}

// Kernel 1c: finalize norms: inv_na/inv_np/exact ap, init top-2 arrays.
__global__ __launch_bounds__(256) void finalize_kernel(
    const float* __restrict__ pa, const float* __restrict__ pp,
    const float* __restrict__ pab, float* __restrict__ inv_na,
    float* __restrict__ inv_np, float* __restrict__ ap,
    u64* __restrict__ arr1, u64* __restrict__ arr2, int B) {
  const int row = blockIdx.x * 256 + threadIdx.x;
  if (row >= B) return;
  float sa = 0.f, sp = 0.f, sab = 0.f;
#pragma unroll
  for (int kg = 0; kg < 8; ++kg) {
    sa += pa[kg * B + row];
    sp += pp[kg * B + row];
    sab += pab[kg * B + row];
  }
  float ina = 1.0f / sqrtf(sa);
  float inp = 1.0f / sqrtf(sp);
  inv_na[row] = ina;
  inv_np[row] = inp;
  ap[row] = sab * ina * inp;
  arr1[row] = 0xFFFFFFFFFFFFFFFFULL;
  arr2[row] = 0xFFFFFFFFFFFFFFFFULL;
}

// Kernel 2: fp8 MFMA GEMM (16x16x32_fp8_fp8, R7-proven fragment path) with
// BK=64 / 16KB LDS: 10 blocks/CU by LDS, ~7 by VGPR -> ~3x the co-resident
// waves of the R7 BK=128 version, so the 16 barrier-drain windows overlap
// across blocks (R7 was stall-bound at ~2.4 blocks/CU, not VALU-bound).
// XCD supertile swizzle. Fused per-row TOP-2 + two-stage atomicMin merge;
// exact fp32 repair in an2_kernel.
__global__ __launch_bounds__(256) void simmin_fp8b(
    const unsigned char* __restrict__ At, const unsigned char* __restrict__ Pt,
    const float* __restrict__ inv_np, u64* __restrict__ arr1,
    u64* __restrict__ arr2, int nb) {
  __shared__ __align__(16) unsigned char As[8192];  // 2 chunks of 4KB
  __shared__ __align__(16) unsigned char Ps[8192];

  const int lid = blockIdx.x;
  int by, bx;
  if (nb == 64) {  // 8x8 supertiles of 8x8 blocks, one supertile set per XCD
    const int xcd = lid & 7;
    const int s = lid >> 3;
    const int st = xcd * 8 + (s >> 6);
    const int u = s & 63;
    by = (st >> 3) * 8 + (u >> 3);
    bx = (st & 7) * 8 + (u & 7);
  } else {
    by = lid / nb;
    bx = lid % nb;
  }

  const int tid = threadIdx.x;
  const int wave = tid >> 6, lane = tid & 63;
  const int wr = wave >> 1, wc = wave & 1;
  const int rowBase = by * 128;
  const int colBase = bx * 128;
  const int c = lane & 15, q = lane >> 4;

  f32x4 acc[4][4];
#pragma unroll
  for (int mt = 0; mt < 4; ++mt)
#pragma unroll
    for (int nt = 0; nt < 4; ++nt) acc[mt][nt] = (f32x4){0.f, 0.f, 0.f, 0.f};

  const unsigned char* Ab = At + (size_t)by * (32 * 4096);  // 128KB slab
  const unsigned char* Pb = Pt + (size_t)bx * (32 * 4096);
  const int loff = wave * 2048;  // 4 waves x 2KB = the 8KB double-chunk
  const int goff = loff + lane * 16;

  // fragment byte-offsets within a 4KB chunk: [(q*128 + tile_row)*8 + j]
  const int aidx = (q * 128 + wr * 64 + c) * 8;
  const int bidx = (q * 128 + wc * 64 + c) * 8;

  for (int kt = 0; kt < 16; ++kt) {  // BK=64: 2 chunks per matrix per window
    const unsigned char* ca = Ab + kt * 8192;
    const unsigned char* cp = Pb + kt * 8192;
    dma16(ca + goff, As + loff);
    dma16(ca + goff + 1024, As + loff + 1024);
    dma16(cp + goff, Ps + loff);
    dma16(cp + goff + 1024, Ps + loff + 1024);
    __syncthreads();  // vmcnt(0) drain + barrier

#pragma unroll
    for (int kk = 0; kk < 2; ++kk) {
      u64 af[4], bfr[4];
#pragma unroll
      for (int mt = 0; mt < 4; ++mt)
        af[mt] = *(const u64*)&As[kk * 4096 + aidx + mt * 128];
#pragma unroll
      for (int nt = 0; nt < 4; ++nt)
        bfr[nt] = *(const u64*)&Ps[kk * 4096 + bidx + nt * 128];
#pragma unroll
      for (int mt = 0; mt < 4; ++mt)
#pragma unroll
        for (int nt = 0; nt < 4; ++nt)
          acc[mt][nt] = __builtin_amdgcn_mfma_f32_16x16x32_fp8_fp8(
              (long)af[mt], (long)bfr[nt], acc[mt][nt], 0, 0, 0);
    }
    __syncthreads();
  }

  // Epilogue: per-row top-2 of v = dot*inv_np[col], j != i.
  // C/D layout: col = lane&15 (=c), row = q*4 + reg.
  float inp_l[4];
#pragma unroll
  for (int nt = 0; nt < 4; ++nt)
    inp_l[nt] = inv_np[colBase + wc * 64 + nt * 16 + c];

#pragma unroll
  for (int mt = 0; mt < 4; ++mt) {
#pragma unroll
    for (int reg = 0; reg < 4; ++reg) {
      const int gi = rowBase + wr * 64 + mt * 16 + q * 4 + reg;
      float v1 = 3.4e38f, v2 = 3.4e38f;
      int i1 = 0, i2 = 0;
#pragma unroll
      for (int nt = 0; nt < 4; ++nt) {
        const int gj = colBase + wc * 64 + nt * 16 + c;
        float v = acc[mt][nt][reg] * inp_l[nt];
        if (gj != gi) {
          if (v < v1) { v2 = v1; i2 = i1; v1 = v; i1 = gj; }
          else if (v < v2) { v2 = v; i2 = gj; }
        }
      }
#pragma unroll
      for (int off = 1; off < 16; off <<= 1) {
        float ov1 = __shfl_xor(v1, off); int oi1 = __shfl_xor(i1, off);
        float ov2 = __shfl_xor(v2, off); int oi2 = __shfl_xor(i2, off);
        float l; int li;
        if (ov1 < v1) { l = v1; li = i1; v1 = ov1; i1 = oi1; }
        else          { l = ov1; li = oi1; }
        if (ov2 < v2) { v2 = ov2; i2 = oi2; }
        if (l < v2)   { v2 = l; i2 = li; }
      }
      if (c == 0) {
        u64 p1 = ((u64)f2mono(v1) << 32) | (unsigned)i1;
        u64 p2 = ((u64)f2mono(v2) << 32) | (unsigned)i2;
        u64 old = atomicMin(&arr1[gi], p1);
        u64 l2 = (old < p1) ? p1 : old;  // loser of the arr1 battle
        if (p2 < l2) l2 = p2;
        atomicMin(&arr2[gi], l2);
      }
    }
  }
}

// Kernel 3: exact fp32 cos for BOTH top-2 candidates; an = min. 1 wave/row.
__global__ __launch_bounds__(256) void an2_kernel(
    const float* __restrict__ A, const float* __restrict__ P,
    const float* __restrict__ inv_na, const float* __restrict__ inv_np,
    const u64* __restrict__ arr1, const u64* __restrict__ arr2,
    float* __restrict__ an, int B) {
  const int row = blockIdx.x * 4 + (threadIdx.x >> 6);
  const int lane = threadIdx.x & 63;
  const unsigned j1 = (unsigned)(arr1[row] & 0xFFFFFFFFULL) & (unsigned)(B - 1);
  const unsigned j2 = (unsigned)(arr2[row] & 0xFFFFFFFFULL) & (unsigned)(B - 1);
  const float4* a4 = (const float4*)(A + (size_t)row * E_DIM);
  const float4* p4a = (const float4*)(P + (size_t)j1 * E_DIM);
  const float4* p4b = (const float4*)(P + (size_t)j2 * E_DIM);
  float s1 = 0.f, s2 = 0.f;
#pragma unroll
  for (int v = 0; v < 4; ++v) {
    const int ci = v * 64 + lane;
    float4 a = a4[ci];
    float4 p = p4a[ci];
    float4 r = p4b[ci];
    s1 += a.x * p.x + a.y * p.y + a.z * p.z + a.w * p.w;
    s2 += a.x * r.x + a.y * r.y + a.z * r.z + a.w * r.w;
  }
#pragma unroll
  for (int off = 32; off > 0; off >>= 1) {
    s1 += __shfl_down(s1, off);
    s2 += __shfl_down(s2, off);
  }
  if (lane == 0) {
    float ina = inv_na[row];
    float c1 = s1 * ina * inv_np[j1];
    float c2 = s2 * ina * inv_np[j2];
    an[row] = (c1 < c2) ? c1 : c2;
  }
}

// Kernel 4: loss_i = relu(1 + ap_i - an_i); out = mean.
__global__ __launch_bounds__(256) void loss_kernel(
    const float* __restrict__ ap, const float* __restrict__ an,
    float* __restrict__ out, int B) {
  const int t = threadIdx.x;
  float s = 0.f;
  for (int i = t; i < B; i += 256) {
    float l = 1.0f + ap[i] - an[i];
    s += (l > 0.f) ? l : 0.f;
  }
#pragma unroll
  for (int off = 32; off > 0; off >>= 1) s += __shfl_down(s, off);
  __shared__ float red[4];
  const int wave = t >> 6, lane = t & 63;
  if (lane == 0) red[wave] = s;
  __syncthreads();
  if (t == 0) out[0] = (red[0] + red[1] + red[2] + red[3]) / (float)B;
}

// ---------- fallback path (ws too small): round-3-proven bf16 pipeline ----
__global__ __launch_bounds__(256) void norms_kernel(
    const float* __restrict__ A, const float* __restrict__ P,
    float* __restrict__ inv_na, float* __restrict__ inv_np,
    float* __restrict__ ap, u64* __restrict__ min64) {
  const int row = blockIdx.x;
  const int t = threadIdx.x;
  const float4* a4 = (const float4*)(A + (size_t)row * E_DIM);
  const float4* p4 = (const float4*)(P + (size_t)row * E_DIM);
  float sa = 0.f, sp = 0.f, sab = 0.f;
  for (int c = t; c < E_DIM / 4; c += 256) {
    float4 a = a4[c];
    float4 p = p4[c];
    sa  += a.x * a.x + a.y * a.y + a.z * a.z + a.w * a.w;
    sp  += p.x * p.x + p.y * p.y + p.z * p.z + p.w * p.w;
    sab += a.x * p.x + a.y * p.y + a.z * p.z + a.w * p.w;
  }
#pragma unroll
  for (int off = 32; off > 0; off >>= 1) {
    sa  += __shfl_down(sa, off);
    sp  += __shfl_down(sp, off);
    sab += __shfl_down(sab, off);
  }
  __shared__ float red[4][3];
  const int wave = t >> 6, lane = t & 63;
  if (lane == 0) { red[wave][0] = sa; red[wave][1] = sp; red[wave][2] = sab; }
  __syncthreads();
  if (t == 0) {
    sa  = red[0][0] + red[1][0] + red[2][0] + red[3][0];
    sp  = red[0][1] + red[1][1] + red[2][1] + red[3][1];
    sab = red[0][2] + red[1][2] + red[2][2] + red[3][2];
    float ina = 1.0f / sqrtf(sa);
    float inp = 1.0f / sqrtf(sp);
    inv_na[row] = ina;
    inv_np[row] = inp;
    ap[row] = sab * ina * inp;
    min64[row] = 0xFFFFFFFFFFFFFFFFULL;
  }
}

__global__ __launch_bounds__(256) void simmin_mfma(
    const float* __restrict__ A, const float* __restrict__ P,
    const float* __restrict__ inv_np, u64* __restrict__ min64) {
  __shared__ __align__(16) short As[128 * 40];
  __shared__ __align__(16) short Ps[128 * 40];

  const int tid = threadIdx.x;
  const int wave = tid >> 6, lane = tid & 63;
  const int wr = wave >> 1, wc = wave & 1;
  const int rowBase = blockIdx.y * 128;
  const int colBase = blockIdx.x * 128;
  const int c = lane & 15, q = lane >> 4;

  f32x4 acc[4][4];
#pragma unroll
  for (int mt = 0; mt < 4; ++mt)
#pragma unroll
    for (int nt = 0; nt < 4; ++nt) acc[mt][nt] = (f32x4){0.f, 0.f, 0.f, 0.f};

  const int sm = tid >> 1;
  const int sh = (tid & 1) * 16;
  const float* Ab = A + (size_t)(rowBase + sm) * E_DIM + sh;
  const float* Pb = P + (size_t)(colBase + sm) * E_DIM + sh;
  uint4* AsW = (uint4*)&As[sm * 40 + sh];
  uint4* PsW = (uint4*)&Ps[sm * 40 + sh];

  for (int kt = 0; kt < E_DIM; kt += 32) {
    float4 a0 = *(const float4*)(Ab + kt);
    float4 a1 = *(const float4*)(Ab + kt + 4);
    float4 a2 = *(const float4*)(Ab + kt + 8);
    float4 a3 = *(const float4*)(Ab + kt + 12);
    float4 p0 = *(const float4*)(Pb + kt);
    float4 p1 = *(const float4*)(Pb + kt + 4);
    float4 p2 = *(const float4*)(Pb + kt + 8);
    float4 p3 = *(const float4*)(Pb + kt + 12);
    uint4 av0 = {pk_bf16(a0.x, a0.y), pk_bf16(a0.z, a0.w),
                 pk_bf16(a1.x, a1.y), pk_bf16(a1.z, a1.w)};
    uint4 av1 = {pk_bf16(a2.x, a2.y), pk_bf16(a2.z, a2.w),
                 pk_bf16(a3.x, a3.y), pk_bf16(a3.z, a3.w)};
    uint4 pv0 = {pk_bf16(p0.x, p0.y), pk_bf16(p0.z, p0.w),
                 pk_bf16(p1.x, p1.y), pk_bf16(p1.z, p1.w)};
    uint4 pv1 = {pk_bf16(p2.x, p2.y), pk_bf16(p2.z, p2.w),
                 pk_bf16(p3.x, p3.y), pk_bf16(p3.z, p3.w)};
    AsW[0] = av0; AsW[1] = av1;
    PsW[0] = pv0; PsW[1] = pv1;
    __syncthreads();

    bf16x8 af[4], bfr[4];
#pragma unroll
    for (int mt = 0; mt < 4; ++mt)
      af[mt] = *(const bf16x8*)&As[(wr * 64 + mt * 16 + c) * 40 + q * 8];
#pragma unroll
    for (int nt = 0; nt < 4; ++nt)
      bfr[nt] = *(const bf16x8*)&Ps[(wc * 64 + nt * 16 + c) * 40 + q * 8];
#pragma unroll
    for (int mt = 0; mt < 4; ++mt)
#pragma unroll
      for (int nt = 0; nt < 4; ++nt)
        acc[mt][nt] = __builtin_amdgcn_mfma_f32_16x16x32_bf16(
            af[mt], bfr[nt], acc[mt][nt], 0, 0, 0);
    __syncthreads();
  }

  float inp_l[4];
#pragma unroll
  for (int nt = 0; nt < 4; ++nt)
    inp_l[nt] = inv_np[colBase + wc * 64 + nt * 16 + c];

#pragma unroll
  for (int mt = 0; mt < 4; ++mt) {
#pragma unroll
    for (int reg = 0; reg < 4; ++reg) {
      const int gi = rowBase + wr * 64 + mt * 16 + q * 4 + reg;
      float best = 3.4e38f;
      int bidx2 = 0;
#pragma unroll
      for (int nt = 0; nt < 4; ++nt) {
        const int gj = colBase + wc * 64 + nt * 16 + c;
        float v = acc[mt][nt][reg] * inp_l[nt];
        if (gj != gi && v < best) { best = v; bidx2 = gj; }
      }
#pragma unroll
      for (int off = 1; off < 16; off <<= 1) {
        float ov = __shfl_xor(best, off);
        int oi = __shfl_xor(bidx2, off);
        if (ov < best) { best = ov; bidx2 = oi; }
      }
      if (c == 0) {
        u64 pk = ((u64)f2mono(best) << 32) | (unsigned)bidx2;
        atomicMin(&min64[gi], pk);
      }
    }
  }
}

extern "C" void kernel_launch(void* const* d_in, const int* in_sizes, int n_in,
                              void* d_out, int out_size, void* d_ws, size_t ws_size,
                              hipStream_t stream) {
  const float* A = (const float*)d_in[0];  // anchor  [B][1024] fp32
  const float* P = (const float*)d_in[1];  // positive[B][1024] fp32
  const int B = in_sizes[0] / E_DIM;       // 8192

  const size_t fp8_elems = (size_t)B * E_DIM;  // bytes per fp8 matrix
  // At | Pt | arr1 | arr2 | partials(3 x 8B floats) | inv_na | inv_np | ap | an
  const size_t need = 2 * fp8_elems + (size_t)B * (16 + 96 + 16) + 64;
  const int nb = B / 128;

  if (ws_size >= need) {
    unsigned char* At = (unsigned char*)d_ws;
    unsigned char* Pt = At + fp8_elems;
    u64* arr1 = (u64*)(Pt + fp8_elems);   // 8B-aligned (16MB offset)
    u64* arr2 = arr1 + B;
    float* pa = (float*)(arr2 + B);
    float* pp = pa + 8 * B;
    float* pab = pp + 8 * B;
    float* inv_na = pab + 8 * B;
    float* inv_np = inv_na + B;
    float* ap = inv_np + B;
    float* an = ap + B;

    normsconv_kernel<<<nb * 8, 256, 0, stream>>>(A, P, At, Pt, pa, pp, pab, B);
    finalize_kernel<<<(B + 255) / 256, 256, 0, stream>>>(
        pa, pp, pab, inv_na, inv_np, ap, arr1, arr2, B);
    simmin_fp8b<<<nb * nb, 256, 0, stream>>>(At, Pt, inv_np, arr1, arr2, nb);
    an2_kernel<<<B / 4, 256, 0, stream>>>(A, P, inv_na, inv_np, arr1, arr2, an, B);
    loss_kernel<<<1, 256, 0, stream>>>(ap, an, (float*)d_out, B);
  } else {
    float* inv_na = (float*)d_ws;
    float* inv_np = inv_na + B;
    float* ap = inv_np + B;
    float* an = ap + B;
    u64* min64 = (u64*)(an + B);
    dim3 grid(nb, nb);

    norms_kernel<<<B, 256, 0, stream>>>(A, P, inv_na, inv_np, ap, min64);
    simmin_mfma<<<grid, 256, 0, stream>>>(A, P, inv_np, min64);
    an2_kernel<<<B / 4, 256, 0, stream>>>(A, P, inv_na, inv_np, min64, min64, an, B);
    loss_kernel<<<1, 256, 0, stream>>>(ap, an, (float*)d_out, B);
  }
}